// Round 17
// baseline (66.870 us; speedup 1.0000x reference)
//
#include <hip/hip_runtime.h>
#include <stdint.h>

#define BB 64
#define NC 1000       // customers per instance
#define KC 10         // clusters
#define MEMCAP 212    // per-cluster member capacity (mean ~100, 11+ sigma)
#define RCAP 64       // per-cluster route capacity (hard max ~43)

__host__ __device__ inline void threefry2x32(uint32_t k0, uint32_t k1,
                                             uint32_t x0, uint32_t x1,
                                             uint32_t* o0, uint32_t* o1) {
  uint32_t k2 = k0 ^ k1 ^ 0x1BD11BDAu;
  x0 += k0; x1 += k1;
#define TF_R(R) { x0 += x1; x1 = (x1 << (R)) | (x1 >> (32 - (R))); x1 ^= x0; }
  TF_R(13) TF_R(15) TF_R(26) TF_R(6)
  x0 += k1; x1 += k2 + 1u;
  TF_R(17) TF_R(29) TF_R(16) TF_R(24)
  x0 += k2; x1 += k0 + 2u;
  TF_R(13) TF_R(15) TF_R(26) TF_R(6)
  x0 += k0; x1 += k1 + 3u;
  TF_R(17) TF_R(29) TF_R(16) TF_R(24)
  x0 += k1; x1 += k2 + 4u;
  TF_R(13) TF_R(15) TF_R(26) TF_R(6)
  x0 += k2; x1 += k0 + 5u;
#undef TF_R
  *o0 = x0; *o1 = x1;
}

__device__ inline uint32_t rand_bits(uint32_t ks0, uint32_t ks1, uint32_t p) {
  uint32_t a, b; threefry2x32(ks0, ks1, 0u, p, &a, &b); return b;
}

// ---- 16-lane DPP helpers (16-lane group = one DPP row; convergent calls) ----
template <int CTRL>
__device__ __forceinline__ void dpp_min_step(unsigned long long& comb,
                                             float& x, float& y) {
  int lo = (int)(uint32_t)comb;
  int hi = (int)(uint32_t)(comb >> 32);
  int olo = __builtin_amdgcn_update_dpp(lo, lo, CTRL, 0xf, 0xf, false);
  int ohi = __builtin_amdgcn_update_dpp(hi, hi, CTRL, 0xf, 0xf, false);
  int oxi = __builtin_amdgcn_update_dpp(__float_as_int(x), __float_as_int(x),
                                        CTRL, 0xf, 0xf, false);
  int oyi = __builtin_amdgcn_update_dpp(__float_as_int(y), __float_as_int(y),
                                        CTRL, 0xf, 0xf, false);
  unsigned long long o =
      ((unsigned long long)(uint32_t)ohi << 32) | (uint32_t)olo;
  if (o < comb) { comb = o; x = __int_as_float(oxi); y = __int_as_float(oyi); }
}

template <int CTRL>
__device__ __forceinline__ void dpp_max_step(unsigned long long& pk, float& x) {
  int lo = (int)(uint32_t)pk;
  int hi = (int)(uint32_t)(pk >> 32);
  int olo = __builtin_amdgcn_update_dpp(lo, lo, CTRL, 0xf, 0xf, false);
  int ohi = __builtin_amdgcn_update_dpp(hi, hi, CTRL, 0xf, 0xf, false);
  int oxi = __builtin_amdgcn_update_dpp(__float_as_int(x), __float_as_int(x),
                                        CTRL, 0xf, 0xf, false);
  unsigned long long o =
      ((unsigned long long)(uint32_t)ohi << 32) | (uint32_t)olo;
  if (o > pk) { pk = o; x = __int_as_float(oxi); }
}

template <int CTRL>
__device__ __forceinline__ float dpp_fmax(float x) {
  int o = __builtin_amdgcn_update_dpp(__float_as_int(x), __float_as_int(x),
                                      CTRL, 0xf, 0xf, false);
  return fmaxf(x, __int_as_float(o));
}

template <int CTRL>
__device__ __forceinline__ float dpp_fadd(float x) {
  int o = __builtin_amdgcn_update_dpp(__float_as_int(x), __float_as_int(x),
                                      CTRL, 0xf, 0xf, false);
  return x + __int_as_float(o);
}

// ---------------------------------------------------------------------------
// Kernel S: 16 lanes per customer (proven r12-r15, absmax 2.5). Unchanged.
// ---------------------------------------------------------------------------
__global__ __launch_bounds__(256) void k_sample(
    const float* __restrict__ logits,   // (64,1001,10)
    uint32_t ks0, uint32_t ks1,
    uint8_t* __restrict__ assign,       // (64,1000)
    float* __restrict__ slp) {          // (64,1000)
  int gtid = blockIdx.x * 256 + threadIdx.x;   // 1,024,000 = 4000*256
  int cust = gtid >> 4;
  int k = gtid & 15;
  int b = cust / NC, n = cust - b * NC;
  const float TINY = 1.1754943508222875e-38f;
  bool actk = (k < KC);

  float x = actk ? logits[((size_t)b * 1001 + (size_t)(n + 1)) * KC + k]
                 : -INFINITY;
  float v = -INFINITY;
  if (actk) {
    uint32_t bits = rand_bits(ks0, ks1, (uint32_t)cust * (uint32_t)KC + (uint32_t)k);
    float f = __uint_as_float((bits >> 9) | 0x3f800000u) - 1.0f;
    float u = (f > 0.0f) ? f : TINY;
    float g = -logf(-logf(u));
    v = g + x;
  }
  uint32_t uv = __float_as_uint(v);
  uint32_t key = (uv & 0x80000000u) ? ~uv : (uv | 0x80000000u);
  unsigned long long pk =
      ((unsigned long long)key << 32) | (uint32_t)(15 - k);  // ties -> min k
  float bwx = x;
  dpp_max_step<0xB1>(pk, bwx);
  dpp_max_step<0x4E>(pk, bwx);
  dpp_max_step<0x141>(pk, bwx);
  dpp_max_step<0x140>(pk, bwx);
  int best_k = 15 - (int)(pk & 0xFu);

  float xm = x;
  xm = dpp_fmax<0xB1>(xm); xm = dpp_fmax<0x4E>(xm);
  xm = dpp_fmax<0x141>(xm); xm = dpp_fmax<0x140>(xm);

  float es = actk ? expf(x - xm) : 0.0f;
  es = dpp_fadd<0xB1>(es); es = dpp_fadd<0x4E>(es);
  es = dpp_fadd<0x141>(es); es = dpp_fadd<0x140>(es);

  if (k == 0) {
    slp[cust] = (bwx - xm) - logf(es);
    assign[cust] = (uint8_t)best_k;
  }
}

// ---------------------------------------------------------------------------
// Kernel R: one wave per cluster, zero barriers (r15-proven, 40.08 us total).
// Unchanged code; launched TWICE this round (second copy to dummy buffers)
// to measure its true duration: R = dur_us - 40.1 - OH.
// ---------------------------------------------------------------------------
__global__ __launch_bounds__(128) void k_route(
    const float* __restrict__ coords,    // (64,1001,2)
    const float* __restrict__ demands,   // (64,1001)
    const float* __restrict__ capacity,  // (64,)
    const uint8_t* __restrict__ assign,  // (64,1000)
    const float* __restrict__ slp,       // (64,1000)
    double* __restrict__ pdistc,         // (64,10) per-cluster route-dist sums
    double* __restrict__ lp) {           // (64,)
  int b = blockIdx.x / 6;
  int blk = blockIdx.x % 6;
  int tid = threadIdx.x;
  int w = tid >> 6, lane = tid & 63;

  __shared__ float memx[2][MEMCAP], memy[2][MEMCAP], demp[2][MEMCAP];
  __shared__ uint16_t rsw[2][RCAP], rlw[2][RCAP];

  // ---- lp block: wave 0 reduces slp[b]; no LDS, no barriers ----
  if (blk == 5) {
    if (w == 0) {
      const float4* s4 = reinterpret_cast<const float4*>(slp + (size_t)b * NC);
      double acc = 0.0;
#pragma unroll
      for (int t = 0; t < 4; ++t) {
        int idx = t * 64 + lane;
        if (idx < 250) {                 // 250 float4 = 1000 floats exactly
          float4 v = s4[idx];
          acc += (double)v.x + (double)v.y + (double)v.z + (double)v.w;
        }
      }
#pragma unroll
      for (int m = 1; m < 64; m <<= 1) acc += __shfl_xor(acc, m);
      if (lane == 0) lp[b] = acc;
    }
    return;
  }

  int myk = blk * 2 + w;                 // this wave's cluster 0..9
  const float2* cb2 = reinterpret_cast<const float2*>(coords + (size_t)b * 1001 * 2);
  const float* db = demands + (size_t)b * 1001;
  const uint8_t* ab = assign + (size_t)b * NC;
  float cap = capacity[b];
  float dx0, dy0;
  { float2 dep = cb2[0]; dx0 = dep.x; dy0 = dep.y; }

  // ---- zero demp (padding correctness for the float4 split walk) ----
#pragma unroll
  for (int t = 0; t < 4; ++t) {
    int i = t * 64 + lane;
    if (i < MEMCAP) demp[w][i] = 0.0f;
  }

  // ---- ballot compaction: stable member order (index order) ----
  int mcount = 0;
  for (int t = 0; t < 16; ++t) {
    int ci = t * 64 + lane;              // customer 0..1023
    bool p = (ci < NC) && (ab[ci] == (uint8_t)myk);
    unsigned long long mk = __ballot(p);
    int rank = __popcll(mk & ((1ull << lane) - 1ull));
    if (p) {
      int pos = mcount + rank;
      if (pos < MEMCAP) {
        float2 c = cb2[ci + 1];
        memx[w][pos] = c.x;
        memy[w][pos] = c.y;
        demp[w][pos] = db[ci + 1];
      }
    }
    mcount += (int)__popcll(mk);
  }
  int M = (mcount < MEMCAP) ? mcount : MEMCAP;

  // ---- capacity split: lane-0 branch-free float4 walk (r14-proven) ----
  int rcount = 0;
  if (lane == 0 && M > 0) {
    const float4* dp4 = reinterpret_cast<const float4*>(&demp[w][0]);
    float load = 0.0f;
    int cur = 0, r = 0;
    int trips = (M + 3) >> 2;            // dp4[trips] <= dp4[52] in-bounds
    float4 cv = dp4[0];
    for (int t = 0; t < trips; ++t) {
      float4 nv = dp4[t + 1];            // prefetch (zero-padded, in-bounds)
#define SPLIT_E(DV, E)                                                        \
      {                                                                       \
        int j = t * 4 + E;                                                    \
        float d = DV;                                                         \
        if (j == 0) load = d;                                                 \
        else if (load + d > cap) {                                            \
          rsw[w][r] = (uint16_t)cur; rlw[w][r] = (uint16_t)(j - cur);         \
          r++; cur = j; load = d;                                             \
        } else load += d;                /* padding d=0: load<=cap -> no-op */\
      }
      SPLIT_E(cv.x, 0) SPLIT_E(cv.y, 1) SPLIT_E(cv.z, 2) SPLIT_E(cv.w, 3)
#undef SPLIT_E
      cv = nv;
    }
    rsw[w][r] = (uint16_t)cur;
    rlw[w][r] = (uint16_t)(M - cur);
    r++;
    rcount = r;
  }
  rcount = __shfl(rcount, 0);            // wave-uniform route count

  // ---- NN: 4 x 16-lane groups round-robin over this cluster's routes ----
  int lane16 = lane & 15;
  int grp = lane >> 4;                   // 0..3
  double gacc = 0.0;

  for (int r = grp; r < rcount; r += 4) {
    int start = rsw[w][r];
    int L = rlw[w][r];

    float mx0 = 0, my0 = 0, mx1 = 0, my1 = 0, mx2 = 0, my2 = 0, mx3 = 0, my3 = 0;
    uint32_t vis = 0;
#define LOADC(c, MX, MY)                                                      \
    { int s = (c) * 16 + lane16;                                              \
      if (s < L) { MX = memx[w][start + s]; MY = memy[w][start + s]; }        \
      else vis |= (1u << (c)); }
    LOADC(0, mx0, my0) LOADC(1, mx1, my1) LOADC(2, mx2, my2) LOADC(3, mx3, my3)
#undef LOADC

    float px = dx0, py = dy0, racc = 0.0f;
    for (int step = 0; step < L; ++step) {
      float bd = INFINITY; int bc = -1; float bx = 0, by = 0;
#define CAND(c, MX, MY)                                                       \
      if (!(vis & (1u << (c)))) {                                             \
        float ddx = MX - px, ddy = MY - py;                                   \
        float d = sqrtf(ddx * ddx + ddy * ddy);                               \
        if (d < bd) { bd = d; bc = (c); bx = MX; by = MY; }                   \
      }
      CAND(0, mx0, my0) CAND(1, mx1, my1) CAND(2, mx2, my2) CAND(3, mx3, my3)
#undef CAND
      unsigned long long comb = (bc < 0)
          ? ~0ull
          : (((unsigned long long)__float_as_uint(bd)) << 32) |
            (unsigned)(bc * 16 + lane16);
      dpp_min_step<0xB1>(comb, bx, by);
      dpp_min_step<0x4E>(comb, bx, by);
      dpp_min_step<0x141>(comb, bx, by);
      dpp_min_step<0x140>(comb, bx, by);
      int slot = (int)(comb & 0xFFFFFFFFull);
      float best = __uint_as_float((uint32_t)(comb >> 32));
      int src16 = slot & 15, cu = slot >> 4;
      if (src16 == lane16) vis |= (1u << cu);
      px = bx; py = by;
      racc += best;                      // f32, reference scan order
    }
    float ddx = px - dx0, ddy = py - dy0;
    racc += sqrtf(ddx * ddx + ddy * ddy); // return-to-depot leg
    gacc += (double)racc;
  }

  // ---- wave-internal reduction of the 4 group partials ----
  {
    double t2 = (lane16 == 0) ? gacc : 0.0;
#pragma unroll
    for (int m = 1; m < 64; m <<= 1) t2 += __shfl_xor(t2, m);
    if (lane == 0) pdistc[b * KC + myk] = t2;
  }
}

// ---------------------------------------------------------------------------
// Kernel C: loss finalize (r15-proven). Unchanged.
// ---------------------------------------------------------------------------
__global__ __launch_bounds__(64) void k_final(
    const double* __restrict__ pdistc,   // (64,10)
    const double* __restrict__ lp,       // (64,)
    float* __restrict__ out) {           // (2,)
  int tid = threadIdx.x;
  double dd = 0.0;
#pragma unroll
  for (int k = 0; k < KC; ++k) dd += pdistc[tid * KC + k];
  float df = (float)dd;
  float lf = (float)lp[tid];
  double m = (double)df;
#pragma unroll
  for (int m2 = 1; m2 < 64; m2 <<= 1) m += __shfl_xor(m, m2);
  double mean = m / 64.0;
  float meanf = (float)mean;
  double li = ((double)df - (double)meanf) * (double)lf;
#pragma unroll
  for (int m2 = 1; m2 < 64; m2 <<= 1) li += __shfl_xor(li, m2);
  if (tid == 0) {
    out[0] = (float)(li / 64.0);
    out[1] = meanf;
  }
}

extern "C" void kernel_launch(void* const* d_in, const int* in_sizes, int n_in,
                              void* d_out, int out_size, void* d_ws, size_t ws_size,
                              hipStream_t stream) {
  const float* logits   = (const float*)d_in[0];  // (64,1001,10)
  const float* coords   = (const float*)d_in[1];  // (64,1001,2)
  const float* demands  = (const float*)d_in[2];  // (64,1001)
  const float* capacity = (const float*)d_in[3];  // (64,)

  uint8_t* ws = (uint8_t*)d_ws;
  double*  pdistc  = (double*)(ws);            // 5120 B
  double*  lp      = (double*)(ws + 8192);     // 512 B
  uint8_t* assign  = (uint8_t*)(ws + 9216);    // 64000 B
  float*   slp     = (float*)(ws + 73216);     // 256000 B
  // dummy outputs for the measurement duplicate (disjoint, never read):
  double*  pdistc2 = (double*)(ws + 331264);   // 5120 B
  double*  lp2     = (double*)(ws + 336896);   // 512 B

  uint32_t ks0, ks1;
  threefry2x32(0u, 42u, 0u, 0u, &ks0, &ks1);   // fold_in(key(42), 0)

  k_sample<<<dim3(BB * NC * 16 / 256), dim3(256), 0, stream>>>(
      logits, ks0, ks1, assign, slp);
  // MEASUREMENT DUPLICATE: identical work, dummy outputs. Deterministic
  // (reads immutable assign/slp; writes disjoint buffers never read).
  k_route<<<dim3(BB * 6), dim3(128), 0, stream>>>(
      coords, demands, capacity, assign, slp, pdistc2, lp2);
  k_route<<<dim3(BB * 6), dim3(128), 0, stream>>>(
      coords, demands, capacity, assign, slp, pdistc, lp);
  k_final<<<dim3(1), dim3(64), 0, stream>>>(pdistc, lp, (float*)d_out);
}

// Round 18
// 33.954 us; speedup vs baseline: 1.9694x; 1.9694x over previous
//
#include <hip/hip_runtime.h>
#include <stdint.h>

#define BB 64
#define NC 1000       // customers per instance
#define KC 10         // clusters
#define MEMCAP 212    // per-cluster member capacity (mean ~100, 11+ sigma)
#define RCAP 64       // per-cluster route capacity (hard max ~43)

__host__ __device__ inline void threefry2x32(uint32_t k0, uint32_t k1,
                                             uint32_t x0, uint32_t x1,
                                             uint32_t* o0, uint32_t* o1) {
  uint32_t k2 = k0 ^ k1 ^ 0x1BD11BDAu;
  x0 += k0; x1 += k1;
#define TF_R(R) { x0 += x1; x1 = (x1 << (R)) | (x1 >> (32 - (R))); x1 ^= x0; }
  TF_R(13) TF_R(15) TF_R(26) TF_R(6)
  x0 += k1; x1 += k2 + 1u;
  TF_R(17) TF_R(29) TF_R(16) TF_R(24)
  x0 += k2; x1 += k0 + 2u;
  TF_R(13) TF_R(15) TF_R(26) TF_R(6)
  x0 += k0; x1 += k1 + 3u;
  TF_R(17) TF_R(29) TF_R(16) TF_R(24)
  x0 += k1; x1 += k2 + 4u;
  TF_R(13) TF_R(15) TF_R(26) TF_R(6)
  x0 += k2; x1 += k0 + 5u;
#undef TF_R
  *o0 = x0; *o1 = x1;
}

__device__ inline uint32_t rand_bits(uint32_t ks0, uint32_t ks1, uint32_t p) {
  uint32_t a, b; threefry2x32(ks0, ks1, 0u, p, &a, &b); return b;
}

// ---- 16-lane DPP helpers (16-lane group = one DPP row; within any group
// ---- taking a branch, all 16 lanes are active -> row sources valid) ----
template <int CTRL>
__device__ __forceinline__ void dpp_min_step(unsigned long long& comb,
                                             float& x, float& y) {
  int lo = (int)(uint32_t)comb;
  int hi = (int)(uint32_t)(comb >> 32);
  int olo = __builtin_amdgcn_update_dpp(lo, lo, CTRL, 0xf, 0xf, false);
  int ohi = __builtin_amdgcn_update_dpp(hi, hi, CTRL, 0xf, 0xf, false);
  int oxi = __builtin_amdgcn_update_dpp(__float_as_int(x), __float_as_int(x),
                                        CTRL, 0xf, 0xf, false);
  int oyi = __builtin_amdgcn_update_dpp(__float_as_int(y), __float_as_int(y),
                                        CTRL, 0xf, 0xf, false);
  unsigned long long o =
      ((unsigned long long)(uint32_t)ohi << 32) | (uint32_t)olo;
  if (o < comb) { comb = o; x = __int_as_float(oxi); y = __int_as_float(oyi); }
}

template <int CTRL>
__device__ __forceinline__ void dpp_max_step(unsigned long long& pk, float& x) {
  int lo = (int)(uint32_t)pk;
  int hi = (int)(uint32_t)(pk >> 32);
  int olo = __builtin_amdgcn_update_dpp(lo, lo, CTRL, 0xf, 0xf, false);
  int ohi = __builtin_amdgcn_update_dpp(hi, hi, CTRL, 0xf, 0xf, false);
  int oxi = __builtin_amdgcn_update_dpp(__float_as_int(x), __float_as_int(x),
                                        CTRL, 0xf, 0xf, false);
  unsigned long long o =
      ((unsigned long long)(uint32_t)ohi << 32) | (uint32_t)olo;
  if (o > pk) { pk = o; x = __int_as_float(oxi); }
}

template <int CTRL>
__device__ __forceinline__ float dpp_fmax(float x) {
  int o = __builtin_amdgcn_update_dpp(__float_as_int(x), __float_as_int(x),
                                      CTRL, 0xf, 0xf, false);
  return fmaxf(x, __int_as_float(o));
}

template <int CTRL>
__device__ __forceinline__ float dpp_fadd(float x) {
  int o = __builtin_amdgcn_update_dpp(__float_as_int(x), __float_as_int(x),
                                      CTRL, 0xf, 0xf, false);
  return x + __int_as_float(o);
}

// ---------------------------------------------------------------------------
// Kernel S: 16 lanes per customer (proven r12-r17, absmax 2.5). Unchanged.
// ---------------------------------------------------------------------------
__global__ __launch_bounds__(256) void k_sample(
    const float* __restrict__ logits,   // (64,1001,10)
    uint32_t ks0, uint32_t ks1,
    uint8_t* __restrict__ assign,       // (64,1000)
    float* __restrict__ slp) {          // (64,1000)
  int gtid = blockIdx.x * 256 + threadIdx.x;   // 1,024,000 = 4000*256
  int cust = gtid >> 4;
  int k = gtid & 15;
  int b = cust / NC, n = cust - b * NC;
  const float TINY = 1.1754943508222875e-38f;
  bool actk = (k < KC);

  float x = actk ? logits[((size_t)b * 1001 + (size_t)(n + 1)) * KC + k]
                 : -INFINITY;
  float v = -INFINITY;
  if (actk) {
    uint32_t bits = rand_bits(ks0, ks1, (uint32_t)cust * (uint32_t)KC + (uint32_t)k);
    float f = __uint_as_float((bits >> 9) | 0x3f800000u) - 1.0f;
    float u = (f > 0.0f) ? f : TINY;
    float g = -logf(-logf(u));
    v = g + x;
  }
  uint32_t uv = __float_as_uint(v);
  uint32_t key = (uv & 0x80000000u) ? ~uv : (uv | 0x80000000u);
  unsigned long long pk =
      ((unsigned long long)key << 32) | (uint32_t)(15 - k);  // ties -> min k
  float bwx = x;
  dpp_max_step<0xB1>(pk, bwx);
  dpp_max_step<0x4E>(pk, bwx);
  dpp_max_step<0x141>(pk, bwx);
  dpp_max_step<0x140>(pk, bwx);
  int best_k = 15 - (int)(pk & 0xFu);

  float xm = x;
  xm = dpp_fmax<0xB1>(xm); xm = dpp_fmax<0x4E>(xm);
  xm = dpp_fmax<0x141>(xm); xm = dpp_fmax<0x140>(xm);

  float es = actk ? expf(x - xm) : 0.0f;
  es = dpp_fadd<0xB1>(es); es = dpp_fadd<0x4E>(es);
  es = dpp_fadd<0x141>(es); es = dpp_fadd<0x140>(es);

  if (k == 0) {
    slp[cust] = (bwx - xm) - logf(es);
    assign[cust] = (uint8_t)best_k;
  }
}

// ---------------------------------------------------------------------------
// Kernel R v2: one wave per cluster, zero barriers. Fixes vs r15 (which
// measured ~24 us via the r17 duplicate-node experiment):
//  (1) compaction is 3 passes — batched assign loads (16 independent loads
//      in flight), VALU-only ballot/rank chain, then independent gathers —
//      instead of 16 serialized memory latencies;
//  (2) NN fast path for L<=16 (99.99% of routes): single-chunk candidate,
//      ~35% shorter per-step chain. Member order, split scan, NN winner and
//      f32 racc order all bit-identical to r15.
// ---------------------------------------------------------------------------
__global__ __launch_bounds__(128) void k_route(
    const float* __restrict__ coords,    // (64,1001,2)
    const float* __restrict__ demands,   // (64,1001)
    const float* __restrict__ capacity,  // (64,)
    const uint8_t* __restrict__ assign,  // (64,1000)
    const float* __restrict__ slp,       // (64,1000)
    double* __restrict__ pdistc,         // (64,10) per-cluster route-dist sums
    double* __restrict__ lp) {           // (64,)
  int b = blockIdx.x / 6;
  int blk = blockIdx.x % 6;
  int tid = threadIdx.x;
  int w = tid >> 6, lane = tid & 63;

  __shared__ float memx[2][MEMCAP], memy[2][MEMCAP], demp[2][MEMCAP];
  __shared__ uint16_t rsw[2][RCAP], rlw[2][RCAP];

  // ---- lp block: wave 0 reduces slp[b]; no LDS, no barriers ----
  if (blk == 5) {
    if (w == 0) {
      const float4* s4 = reinterpret_cast<const float4*>(slp + (size_t)b * NC);
      double acc = 0.0;
#pragma unroll
      for (int t = 0; t < 4; ++t) {
        int idx = t * 64 + lane;
        if (idx < 250) {                 // 250 float4 = 1000 floats exactly
          float4 v = s4[idx];
          acc += (double)v.x + (double)v.y + (double)v.z + (double)v.w;
        }
      }
#pragma unroll
      for (int m = 1; m < 64; m <<= 1) acc += __shfl_xor(acc, m);
      if (lane == 0) lp[b] = acc;
    }
    return;
  }

  int myk = blk * 2 + w;                 // this wave's cluster 0..9
  const float2* cb2 = reinterpret_cast<const float2*>(coords + (size_t)b * 1001 * 2);
  const float* db = demands + (size_t)b * 1001;
  const uint8_t* ab = assign + (size_t)b * NC;
  float cap = capacity[b];
  float dx0, dy0;
  { float2 dep = cb2[0]; dx0 = dep.x; dy0 = dep.y; }

  // ---- zero demp (padding correctness for the float4 split walk) ----
#pragma unroll
  for (int t = 0; t < 4; ++t) {
    int i = t * 64 + lane;
    if (i < MEMCAP) demp[w][i] = 0.0f;
  }

  // ---- pass 1: batched assign loads (16 independent, one latency) ----
  uint8_t avl[16];
#pragma unroll
  for (int t = 0; t < 16; ++t) {
    int ci = t * 64 + lane;
    avl[t] = (ci < NC) ? ab[ci] : (uint8_t)0xFF;
  }

  // ---- pass 2: VALU-only ballot/rank chain (stable index order) ----
  unsigned long long lmask = (1ull << lane) - 1ull;
  int posl[16];
  bool pl[16];
  int mcount = 0;
#pragma unroll
  for (int t = 0; t < 16; ++t) {
    bool p = (avl[t] == (uint8_t)myk);
    unsigned long long mk = __ballot(p);
    pl[t] = p;
    posl[t] = mcount + (int)__popcll(mk & lmask);
    mcount += (int)__popcll(mk);
  }

  // ---- pass 3: independent gathers + LDS scatter (overlapped latency) ----
#pragma unroll
  for (int t = 0; t < 16; ++t) {
    int ci = t * 64 + lane;
    if (pl[t] && posl[t] < MEMCAP) {
      float2 c = cb2[ci + 1];
      memx[w][posl[t]] = c.x;
      memy[w][posl[t]] = c.y;
      demp[w][posl[t]] = db[ci + 1];
    }
  }
  int M = (mcount < MEMCAP) ? mcount : MEMCAP;

  // ---- capacity split: lane-0 branch-free float4 walk (r14-proven) ----
  int rcount = 0;
  if (lane == 0 && M > 0) {
    const float4* dp4 = reinterpret_cast<const float4*>(&demp[w][0]);
    float load = 0.0f;
    int cur = 0, r = 0;
    int trips = (M + 3) >> 2;            // dp4[trips] <= dp4[52] in-bounds
    float4 cv = dp4[0];
    for (int t = 0; t < trips; ++t) {
      float4 nv = dp4[t + 1];            // prefetch (zero-padded, in-bounds)
#define SPLIT_E(DV, E)                                                        \
      {                                                                       \
        int j = t * 4 + E;                                                    \
        float d = DV;                                                         \
        if (j == 0) load = d;                                                 \
        else if (load + d > cap) {                                            \
          rsw[w][r] = (uint16_t)cur; rlw[w][r] = (uint16_t)(j - cur);         \
          r++; cur = j; load = d;                                             \
        } else load += d;                /* padding d=0: load<=cap -> no-op */\
      }
      SPLIT_E(cv.x, 0) SPLIT_E(cv.y, 1) SPLIT_E(cv.z, 2) SPLIT_E(cv.w, 3)
#undef SPLIT_E
      cv = nv;
    }
    rsw[w][r] = (uint16_t)cur;
    rlw[w][r] = (uint16_t)(M - cur);
    r++;
    rcount = r;
  }
  rcount = __shfl(rcount, 0);            // wave-uniform route count

  // ---- NN: 4 x 16-lane groups round-robin over this cluster's routes ----
  int lane16 = lane & 15;
  int grp = lane >> 4;                   // 0..3
  double gacc = 0.0;

  for (int r = grp; r < rcount; r += 4) {
    int start = rsw[w][r];
    int L = rlw[w][r];
    float px = dx0, py = dy0, racc = 0.0f;

    if (L <= 16) {
      // fast path: member j = lane16; single candidate per lane.
      float mx = 0.0f, my = 0.0f;
      bool act = (lane16 < L);
      if (act) { mx = memx[w][start + lane16]; my = memy[w][start + lane16]; }
      uint32_t unv = act ? 1u : 0u;      // unvisited flag
      for (int step = 0; step < L; ++step) {
        float bd = INFINITY, bx = 0.0f, by = 0.0f;
        if (unv) {
          float ddx = mx - px, ddy = my - py;
          bd = sqrtf(ddx * ddx + ddy * ddy);
          bx = mx; by = my;
        }
        unsigned long long comb = unv
            ? ((((unsigned long long)__float_as_uint(bd)) << 32) |
               (unsigned)lane16)         // ties -> min member index
            : ~0ull;
        dpp_min_step<0xB1>(comb, bx, by);
        dpp_min_step<0x4E>(comb, bx, by);
        dpp_min_step<0x141>(comb, bx, by);
        dpp_min_step<0x140>(comb, bx, by);
        int wl = (int)(comb & 0xFFFFFFFFull);
        float best = __uint_as_float((uint32_t)(comb >> 32));
        if (wl == (int)lane16) unv = 0;
        px = bx; py = by;
        racc += best;                    // f32, reference scan order
      }
    } else {
      // generic 4-chunk path (rare: P(L>16) ~ 7e-5; r15-proven)
      float mx0 = 0, my0 = 0, mx1 = 0, my1 = 0, mx2 = 0, my2 = 0, mx3 = 0, my3 = 0;
      uint32_t vis = 0;
#define LOADC(c, MX, MY)                                                      \
      { int s = (c) * 16 + lane16;                                            \
        if (s < L) { MX = memx[w][start + s]; MY = memy[w][start + s]; }      \
        else vis |= (1u << (c)); }
      LOADC(0, mx0, my0) LOADC(1, mx1, my1) LOADC(2, mx2, my2) LOADC(3, mx3, my3)
#undef LOADC
      for (int step = 0; step < L; ++step) {
        float bd = INFINITY; int bc = -1; float bx = 0, by = 0;
#define CAND(c, MX, MY)                                                       \
        if (!(vis & (1u << (c)))) {                                           \
          float ddx = MX - px, ddy = MY - py;                                 \
          float d = sqrtf(ddx * ddx + ddy * ddy);                             \
          if (d < bd) { bd = d; bc = (c); bx = MX; by = MY; }                 \
        }
        CAND(0, mx0, my0) CAND(1, mx1, my1) CAND(2, mx2, my2) CAND(3, mx3, my3)
#undef CAND
        unsigned long long comb = (bc < 0)
            ? ~0ull
            : (((unsigned long long)__float_as_uint(bd)) << 32) |
              (unsigned)(bc * 16 + lane16);
        dpp_min_step<0xB1>(comb, bx, by);
        dpp_min_step<0x4E>(comb, bx, by);
        dpp_min_step<0x141>(comb, bx, by);
        dpp_min_step<0x140>(comb, bx, by);
        int slot = (int)(comb & 0xFFFFFFFFull);
        float best = __uint_as_float((uint32_t)(comb >> 32));
        int src16 = slot & 15, cu = slot >> 4;
        if (src16 == (int)lane16) vis |= (1u << cu);
        px = bx; py = by;
        racc += best;                    // f32, reference scan order
      }
    }
    float ddx = px - dx0, ddy = py - dy0;
    racc += sqrtf(ddx * ddx + ddy * ddy); // return-to-depot leg
    gacc += (double)racc;
  }

  // ---- wave-internal reduction of the 4 group partials ----
  {
    double t2 = (lane16 == 0) ? gacc : 0.0;
#pragma unroll
    for (int m = 1; m < 64; m <<= 1) t2 += __shfl_xor(t2, m);
    if (lane == 0) pdistc[b * KC + myk] = t2;
  }
}

// ---------------------------------------------------------------------------
// Kernel C: loss finalize (r15-proven). Unchanged.
// ---------------------------------------------------------------------------
__global__ __launch_bounds__(64) void k_final(
    const double* __restrict__ pdistc,   // (64,10)
    const double* __restrict__ lp,       // (64,)
    float* __restrict__ out) {           // (2,)
  int tid = threadIdx.x;
  double dd = 0.0;
#pragma unroll
  for (int k = 0; k < KC; ++k) dd += pdistc[tid * KC + k];
  float df = (float)dd;
  float lf = (float)lp[tid];
  double m = (double)df;
#pragma unroll
  for (int m2 = 1; m2 < 64; m2 <<= 1) m += __shfl_xor(m, m2);
  double mean = m / 64.0;
  float meanf = (float)mean;
  double li = ((double)df - (double)meanf) * (double)lf;
#pragma unroll
  for (int m2 = 1; m2 < 64; m2 <<= 1) li += __shfl_xor(li, m2);
  if (tid == 0) {
    out[0] = (float)(li / 64.0);
    out[1] = meanf;
  }
}

extern "C" void kernel_launch(void* const* d_in, const int* in_sizes, int n_in,
                              void* d_out, int out_size, void* d_ws, size_t ws_size,
                              hipStream_t stream) {
  const float* logits   = (const float*)d_in[0];  // (64,1001,10)
  const float* coords   = (const float*)d_in[1];  // (64,1001,2)
  const float* demands  = (const float*)d_in[2];  // (64,1001)
  const float* capacity = (const float*)d_in[3];  // (64,)

  uint8_t* ws = (uint8_t*)d_ws;
  double*  pdistc = (double*)(ws);            // 5120 B
  double*  lp     = (double*)(ws + 8192);     // 512 B
  uint8_t* assign = (uint8_t*)(ws + 9216);    // 64000 B
  float*   slp    = (float*)(ws + 73216);     // 256000 B

  uint32_t ks0, ks1;
  threefry2x32(0u, 42u, 0u, 0u, &ks0, &ks1);   // fold_in(key(42), 0)

  k_sample<<<dim3(BB * NC * 16 / 256), dim3(256), 0, stream>>>(
      logits, ks0, ks1, assign, slp);
  k_route<<<dim3(BB * 6), dim3(128), 0, stream>>>(
      coords, demands, capacity, assign, slp, pdistc, lp);
  k_final<<<dim3(1), dim3(64), 0, stream>>>(pdistc, lp, (float*)d_out);
}